// Round 3
// baseline (16.233 us; speedup 1.0000x reference)
//
#include <hip/hip_runtime.h>

// Problem geometry (fixed by the reference module config)
#define IC    8
#define OC    16
#define H     32
#define W     32
#define PH    34
#define PW    34
#define OH    32
#define OW    32
#define BATCH 64
#define WCOLS (IC * PH * PW)   // 9248 columns of the Toeplitz weight
#define XSTR  35               // LDS row stride (floats): odd -> <=2-way bank alias (free)
#define PLANE (PH * XSTR)      // 34*35 = 1190 floats per input-channel plane

// One block per (batch, oc-pair); 256 threads in two ic-halves (split-K over ic).
// Each thread: 1x8 output strip x 2 ocs x 4 ics; halves combine via LDS partials.
__global__ __launch_bounds__(256, 2) void conv_split_kernel(
    const float* __restrict__ x,       // [B, IC*H*W]
    const float* __restrict__ weight,  // [OC*OH*OW, WCOLS] Toeplitz
    const float* __restrict__ bias,    // [OC*OH*OW]
    float* __restrict__ out)           // [B, OC*OH*OW]
{
    __shared__ float xs[IC * PLANE];       // 9520 floats = 38080 B, zero-padded planes
    __shared__ float pbuf[4 * 128 * 4];    // 2048 floats = 8192 B, partial exchange

    const int tid = threadIdx.x;
    const int blk = blockIdx.x;
    const int b   = blk >> 3;              // batch index
    const int oc0 = (blk & 7) << 1;        // first oc of the pair

    // ---- zero ONLY the halo cells the compute phase can read ----
    // per plane: rows 0,33 cols 0..33 (68) + cols 0,33 of rows 1..32 (64) = 132
    for (int i = tid; i < IC * 132; i += 256) {
        const int p = i / 132;
        const int r = i - p * 132;
        int row, col;
        if (r < 34)       { row = 0;       col = r;      }
        else if (r < 68)  { row = 33;      col = r - 34; }
        else if (r < 100) { row = r - 67;  col = 0;      }   // rows 1..32
        else              { row = r - 99;  col = 33;     }
        xs[p * PLANE + row * XSTR + col] = 0.0f;
    }

    // ---- stage x[b] into the interior (coalesced float4 global loads) ----
    const float4* xg = (const float4*)(x + (size_t)b * (IC * H * W));
    #pragma unroll
    for (int i = 0; i < 8; ++i) {
        const int k   = tid + (i << 8);     // float4 index, 0..2047
        const float4 v = xg[k];
        const int ic  = k >> 8;             // 256 float4 per channel plane
        const int rem = k & 255;
        const int h   = rem >> 3;           // 8 float4 per row
        const int w4  = (rem & 7) << 2;
        float* dst = &xs[ic * PLANE + (h + 1) * XSTR + (w4 + 1)];
        dst[0] = v.x; dst[1] = v.y; dst[2] = v.z; dst[3] = v.w;
    }

    // ---- wave-uniform weight fetch straight from global (no LDS, no DS-pipe) ----
    const int half = tid >> 7;                                  // 0: ic 0-3, 1: ic 4-7
    const int t    = tid & 127;
    const int icb  = __builtin_amdgcn_readfirstlane(half << 2); // wave-uniform by construction
    float wreg[2][4][3][3];
    #pragma unroll
    for (int os = 0; os < 2; ++os)
        #pragma unroll
        for (int i = 0; i < 4; ++i)
            #pragma unroll
            for (int kh = 0; kh < 3; ++kh)
                #pragma unroll
                for (int kw = 0; kw < 3; ++kw)
                    wreg[os][i][kh][kw] =
                        weight[(size_t)((oc0 + os) << 10) * WCOLS
                               + ((icb + i) * PH + kh) * PW + kw];

    __syncthreads();

    // ---- compute: 1x8 strip at (oh, ow0..ow0+7), 2 ocs, this half's 4 ics ----
    const int oh  = t >> 2;            // 0..31
    const int ow0 = (t & 3) << 3;      // 0,8,16,24

    float acc[2][8];
    #pragma unroll
    for (int os = 0; os < 2; ++os)
        #pragma unroll
        for (int j = 0; j < 8; ++j) acc[os][j] = 0.0f;

    #pragma unroll
    for (int i = 0; i < 4; ++i) {
        #pragma unroll
        for (int kh = 0; kh < 3; ++kh) {
            const float* rp = &xs[(icb + i) * PLANE + (oh + kh) * XSTR + ow0];
            float v[10];
            #pragma unroll
            for (int d = 0; d < 10; ++d) v[d] = rp[d];
            #pragma unroll
            for (int os = 0; os < 2; ++os) {
                const float w0 = wreg[os][i][kh][0];
                const float w1 = wreg[os][i][kh][1];
                const float w2 = wreg[os][i][kh][2];
                #pragma unroll
                for (int j = 0; j < 8; ++j)
                    acc[os][j] += v[j] * w0 + v[j + 1] * w1 + v[j + 2] * w2;
            }
        }
    }

    // ---- half 0 publishes partials ([quad][thread][4] layout: b128, 8-quad spread) ----
    if (half == 0) {
        #pragma unroll
        for (int q = 0; q < 4; ++q) {
            const int os = q >> 1, j0 = (q & 1) << 2;
            float4 pv = make_float4(acc[os][j0], acc[os][j0 + 1],
                                    acc[os][j0 + 2], acc[os][j0 + 3]);
            *(float4*)&pbuf[(q * 128 + t) * 4] = pv;
        }
    }
    __syncthreads();

    // ---- half 1 combines, adds bias, stores ----
    if (half == 1) {
        const int oidx = (oh << 5) + ow0;
        #pragma unroll
        for (int os = 0; os < 2; ++os) {
            const float4 bv0 = *(const float4*)(bias + ((oc0 + os) << 10) + oidx);
            const float4 bv1 = *(const float4*)(bias + ((oc0 + os) << 10) + oidx + 4);
            const float4 p0  = *(const float4*)&pbuf[((os * 2 + 0) * 128 + t) * 4];
            const float4 p1  = *(const float4*)&pbuf[((os * 2 + 1) * 128 + t) * 4];
            float4 o0 = make_float4(acc[os][0] + p0.x + bv0.x, acc[os][1] + p0.y + bv0.y,
                                    acc[os][2] + p0.z + bv0.z, acc[os][3] + p0.w + bv0.w);
            float4 o1 = make_float4(acc[os][4] + p1.x + bv1.x, acc[os][5] + p1.y + bv1.y,
                                    acc[os][6] + p1.z + bv1.z, acc[os][7] + p1.w + bv1.w);
            float* op = out + (size_t)(((b << 4) + oc0 + os) << 10) + oidx;
            *(float4*)op       = o0;
            *(float4*)(op + 4) = o1;
        }
    }
}

extern "C" void kernel_launch(void* const* d_in, const int* in_sizes, int n_in,
                              void* d_out, int out_size, void* d_ws, size_t ws_size,
                              hipStream_t stream) {
    const float* x      = (const float*)d_in[0];  // enc_x  [64, 8192]
    const float* weight = (const float*)d_in[1];  // weight [16384, 9248]
    const float* bias   = (const float*)d_in[2];  // bias   [16384]
    // d_in[3] = pad_mat: realized structurally via the LDS halo.
    float* out = (float*)d_out;                   // [64, 16384]

    conv_split_kernel<<<dim3(BATCH * (OC / 2)), dim3(256), 0, stream>>>(x, weight, bias, out);
}

// Round 4
// 14.034 us; speedup vs baseline: 1.1566x; 1.1566x over previous
//
#include <hip/hip_runtime.h>

// Problem geometry (fixed by the reference module config)
#define IC    8
#define OC    16
#define H     32
#define W     32
#define PH    34
#define PW    34
#define BATCH 64
#define WCOLS (IC * PH * PW)   // 9248
#define XSTR  35               // LDS row stride: odd -> uniform <=2-way bank alias (free)
#define TROWS 18               // padded rows staged per half-plane
#define PLANE (TROWS * XSTR)   // 630 floats per channel plane

// Block = (batch, 4-oc quad, half-plane). 128 threads.
// Thread = 1x4 output strip for ALL 4 ocs (window LDS reads shared 4 ways).
__global__ __launch_bounds__(128, 2) void conv_quad_kernel(
    const float* __restrict__ x,       // [B, IC*H*W]
    const float* __restrict__ weight,  // [OC*OH*OW, WCOLS] Toeplitz
    const float* __restrict__ bias,    // [OC*OH*OW]
    float* __restrict__ out)           // [B, OC*OH*OW]
{
    __shared__ float xs[IC * PLANE];   // 5040 floats = 20160 B
    __shared__ float wk[IC * 36];      // [ic][oc 0..3][kh][kw], 1152 B

    const int t   = threadIdx.x;
    const int blk = blockIdx.x;
    const int b   = blk >> 3;          // batch
    const int q   = (blk >> 1) & 3;    // oc quad
    const int hf  = blk & 1;           // which half of the image
    const int oc0 = q << 2;
    const int dr0 = hf ? 15 : 0;       // first data row staged
    const int lr0 = hf ? 0 : 1;        // local row receiving it
    const int lrh = hf ? 17 : 0;       // the all-zero halo row
    const int oh0 = hf << 4;

    // ---- weights -> LDS once (global scatter, L2-warm across the 128 sharing blocks) ----
    for (int v = t; v < IC * 36; v += 128) {
        const int ic = v / 36;
        const int r  = v - ic * 36;
        const int oc = r / 9;
        const int k  = r - oc * 9;
        const int kh = k / 3;
        const int kw = k - kh * 3;
        wk[v] = weight[(size_t)((oc0 + oc) << 10) * WCOLS + (ic * PH + kh) * PW + kw];
    }

    // ---- zero only the halo: cols 0/33 of all 18 rows + the one full halo row ----
    #pragma unroll
    for (int ic = 0; ic < IC; ++ic) {
        if (t < 71) {
            int row, col;
            if (t < 36) { row = t >> 1; col = (t & 1) ? 33 : 0; }
            else        { row = lrh;    col = t - 36; }          // 0..34
            xs[ic * PLANE + row * XSTR + col] = 0.0f;
        }
    }

    // ---- stage 17 data rows per ic (coalesced float4 loads) ----
    const float4* xg = (const float4*)(x + ((size_t)b << 13));
    #pragma unroll
    for (int ic = 0; ic < IC; ++ic) {
        for (int j = t; j < 136; j += 128) {       // 17 rows x 8 float4
            const int h  = j >> 3;
            const int w4 = (j & 7) << 2;
            const float4 v = xg[(ic << 8) + ((dr0 + h) << 3) + (j & 7)];
            float* dst = &xs[ic * PLANE + (lr0 + h) * XSTR + w4 + 1];
            dst[0] = v.x; dst[1] = v.y; dst[2] = v.z; dst[3] = v.w;
        }
    }
    __syncthreads();

    // ---- compute: 1x4 strip at (oh0+r, ow0..ow0+3) for 4 ocs ----
    const int r   = t >> 3;            // 0..15
    const int ow0 = (t & 7) << 2;      // 0..28

    float acc[4][4];
    #pragma unroll
    for (int oc = 0; oc < 4; ++oc)
        #pragma unroll
        for (int j = 0; j < 4; ++j) acc[oc][j] = 0.0f;

    #pragma unroll
    for (int ic = 0; ic < IC; ++ic) {
        // hoist this ic's 36 weights via uniform-address b128 (broadcast, cheap)
        float w[36];
        #pragma unroll
        for (int i = 0; i < 9; ++i)
            *(float4*)&w[i * 4] = *(const float4*)&wk[ic * 36 + i * 4];

        #pragma unroll
        for (int kh = 0; kh < 3; ++kh) {
            const float* rp = &xs[ic * PLANE + (r + kh) * XSTR + ow0];
            const float v0 = rp[0], v1 = rp[1], v2 = rp[2];
            const float v3 = rp[3], v4 = rp[4], v5 = rp[5];
            #pragma unroll
            for (int oc = 0; oc < 4; ++oc) {
                const float w0 = w[oc * 9 + kh * 3];
                const float w1 = w[oc * 9 + kh * 3 + 1];
                const float w2 = w[oc * 9 + kh * 3 + 2];
                acc[oc][0] += v0 * w0 + v1 * w1 + v2 * w2;
                acc[oc][1] += v1 * w0 + v2 * w1 + v3 * w2;
                acc[oc][2] += v2 * w0 + v3 * w1 + v4 * w2;
                acc[oc][3] += v3 * w0 + v4 * w1 + v5 * w2;
            }
        }
    }

    // ---- epilogue: add bias, store (b128, coalesced per oc) ----
    const int oidx = ((oh0 + r) << 5) + ow0;
    #pragma unroll
    for (int oc = 0; oc < 4; ++oc) {
        const float4 bv = *(const float4*)(bias + ((oc0 + oc) << 10) + oidx);
        float4 o = make_float4(acc[oc][0] + bv.x, acc[oc][1] + bv.y,
                               acc[oc][2] + bv.z, acc[oc][3] + bv.w);
        *(float4*)(out + (size_t)(((b << 4) + oc0 + oc) << 10) + oidx) = o;
    }
}

extern "C" void kernel_launch(void* const* d_in, const int* in_sizes, int n_in,
                              void* d_out, int out_size, void* d_ws, size_t ws_size,
                              hipStream_t stream) {
    const float* x      = (const float*)d_in[0];  // enc_x  [64, 8192]
    const float* weight = (const float*)d_in[1];  // weight [16384, 9248]
    const float* bias   = (const float*)d_in[2];  // bias   [16384]
    // d_in[3] = pad_mat: realized structurally via the LDS halo.
    float* out = (float*)d_out;                   // [64, 16384]

    conv_quad_kernel<<<dim3(BATCH * 8), dim3(128), 0, stream>>>(x, weight, bias, out);
}

// Round 5
// 13.647 us; speedup vs baseline: 1.1895x; 1.0284x over previous
//
#include <hip/hip_runtime.h>

// Problem geometry (fixed by the reference module config)
#define IC    8
#define OC    16
#define H     32
#define W     32
#define PH    34          // padded rows (and cols) = 34
#define BATCH 64
#define WCOLS 9248        // IC*34*34
#define XSTR  36          // LDS row stride in floats: multiple of 4 -> aligned b128 reads
#define PLANE (PH * XSTR) // 34*36 = 1224 floats per channel plane
#define NDATA 2304        // 8 ic * 32 data rows * 9 groups
#define NGRP  2448        // + 8 ic * 2 zero rows * 9 groups

// Block = (batch, oc-pair), 256 threads, full padded image in LDS.
// Thread = 1x4 output strip for both ocs. All LDS traffic vectorized.
__global__ __launch_bounds__(256, 2) void conv_pair_v5_kernel(
    const float* __restrict__ x,       // [B, IC*H*W]
    const float* __restrict__ weight,  // [OC*OH*OW, WCOLS] Toeplitz
    const float* __restrict__ bias,    // [OC*OH*OW]
    float* __restrict__ out)           // [B, OC*OH*OW]
{
    __shared__ float wk[16 * 12];      // [(ic*2+os)*12 + kh*3+kw], 12-float stride: b128-aligned
    __shared__ float xs[IC * PLANE];   // 9792 floats = 39168 B, padded planes

    const int tid = threadIdx.x;
    const int blk = blockIdx.x;
    const int b   = blk >> 3;          // batch
    const int oc0 = (blk & 7) << 1;    // first oc of the pair

    // ---- weights -> LDS (global gather; 144 scattered but L2-hot reads) ----
    if (tid < 144) {
        const int os = tid / 72;
        const int k  = tid - os * 72;          // 0..71
        const int ic = k / 9;
        const int r  = k - ic * 9;
        const int kh = r / 3;
        const int kw = r - kh * 3;
        wk[(ic * 2 + os) * 12 + r] =
            weight[(size_t)((oc0 + os) << 10) * WCOLS + (ic * PH + kh) * PH + kw];
    }

    // ---- stage padded image as aligned float4 groups (pad folded in registers) ----
    // group layout per padded row (36 cols): g=0:[0,x0,x1,x2], g=1..7:[x(4g-1)..x(4g+2)],
    // g=8:[x31,0,0,0]; rows 0 and 33 are all-zero groups.
    const float* xb = x + ((size_t)b << 13);
    float4 vals[10];
    int    dsta[10];
    #pragma unroll
    for (int it = 0; it < 10; ++it) {
        const int idx = tid + (it << 8);
        float4 v = make_float4(0.f, 0.f, 0.f, 0.f);
        int ic, row, g;
        if (idx < NDATA) {
            ic = idx / 288;                      // 288 = 32 rows * 9 groups
            const int rem = idx - ic * 288;
            row = rem / 9 + 1;                   // data rows 1..32
            g   = rem - (row - 1) * 9;
            const int o = ((ic << 5) + (row - 1)) << 5;   // x row base
            if (g == 0)      v = make_float4(0.f, xb[o], xb[o + 1], xb[o + 2]);
            else if (g == 8) v = make_float4(xb[o + 31], 0.f, 0.f, 0.f);
            else {
                const float* p = xb + o + (g << 2) - 1;
                v = make_float4(p[0], p[1], p[2], p[3]);
            }
        } else {                                  // zero rows (0 and 33)
            const int z = idx - NDATA;            // 0..143
            ic = z / 18;
            const int zz = z - ic * 18;
            row = (zz >= 9) ? 33 : 0;
            g   = (zz >= 9) ? zz - 9 : zz;
        }
        vals[it] = v;
        dsta[it] = ic * PLANE + row * XSTR + (g << 2);
    }
    #pragma unroll
    for (int it = 0; it < 10; ++it) {
        const int idx = tid + (it << 8);
        if (idx < NGRP) *(float4*)&xs[dsta[it]] = vals[it];
    }
    __syncthreads();

    // ---- compute: 1x4 strip at (oh, ow0..ow0+3) for both ocs ----
    const int oh   = tid >> 3;         // 0..31
    const int ow0  = (tid & 7) << 2;   // 0,4,...,28
    const int oidx = (oh << 5) + ow0;

    const float4 b0 = *(const float4*)(bias + (oc0 << 10) + oidx);
    const float4 b1 = *(const float4*)(bias + ((oc0 + 1) << 10) + oidx);
    float a00 = b0.x, a01 = b0.y, a02 = b0.z, a03 = b0.w;
    float a10 = b1.x, a11 = b1.y, a12 = b1.z, a13 = b1.w;

    #pragma unroll
    for (int ic = 0; ic < IC; ++ic) {
        // hoist this ic's 18 weights via broadcast (uniform-address) b128 reads
        float w[2][12];
        #pragma unroll
        for (int os = 0; os < 2; ++os)
            #pragma unroll
            for (int i = 0; i < 3; ++i)
                *(float4*)&w[os][i * 4] = *(const float4*)&wk[(ic * 2 + os) * 12 + i * 4];

        #pragma unroll
        for (int kh = 0; kh < 3; ++kh) {
            const float* rp = &xs[ic * PLANE + (oh + kh) * XSTR + ow0];
            const float4 va = *(const float4*)rp;        // 16B aligned
            const float2 vb = *(const float2*)(rp + 4);  // 16B aligned
            const float v0 = va.x, v1 = va.y, v2 = va.z, v3 = va.w;
            const float v4 = vb.x, v5 = vb.y;
            {
                const float w0 = w[0][kh * 3], w1 = w[0][kh * 3 + 1], w2 = w[0][kh * 3 + 2];
                a00 += v0 * w0 + v1 * w1 + v2 * w2;
                a01 += v1 * w0 + v2 * w1 + v3 * w2;
                a02 += v2 * w0 + v3 * w1 + v4 * w2;
                a03 += v3 * w0 + v4 * w1 + v5 * w2;
            }
            {
                const float w0 = w[1][kh * 3], w1 = w[1][kh * 3 + 1], w2 = w[1][kh * 3 + 2];
                a10 += v0 * w0 + v1 * w1 + v2 * w2;
                a11 += v1 * w0 + v2 * w1 + v3 * w2;
                a12 += v2 * w0 + v3 * w1 + v4 * w2;
                a13 += v3 * w0 + v4 * w1 + v5 * w2;
            }
        }
    }

    float* o0 = out + (size_t)(((b << 4) + oc0) << 10) + oidx;
    *(float4*)o0 = make_float4(a00, a01, a02, a03);
    *(float4*)(o0 + 1024) = make_float4(a10, a11, a12, a13);
}

extern "C" void kernel_launch(void* const* d_in, const int* in_sizes, int n_in,
                              void* d_out, int out_size, void* d_ws, size_t ws_size,
                              hipStream_t stream) {
    const float* x      = (const float*)d_in[0];  // enc_x  [64, 8192]
    const float* weight = (const float*)d_in[1];  // weight [16384, 9248]
    const float* bias   = (const float*)d_in[2];  // bias   [16384]
    // d_in[3] = pad_mat: realized structurally (pad folded into staging registers).
    float* out = (float*)d_out;                   // [64, 16384]

    conv_pair_v5_kernel<<<dim3(BATCH * 8), dim3(256), 0, stream>>>(x, weight, bias, out);
}

// Round 6
// 13.637 us; speedup vs baseline: 1.1903x; 1.0007x over previous
//
#include <hip/hip_runtime.h>

// Problem geometry (fixed by the reference module config)
#define IC    8
#define OC    16
#define H     32
#define W     32
#define BATCH 64
#define WCOLS 9248        // IC*34*34 columns of the Toeplitz weight

// No LDS, no barriers. Block = (batch, oc-pair, image half), 128 threads.
// Thread = 1x4 output strip for both ocs, reading x directly (L1/L2-resident).
__global__ __launch_bounds__(128) void conv_direct_kernel(
    const float* __restrict__ x,       // [B, IC*H*W]
    const float* __restrict__ weight,  // [OC*OH*OW, WCOLS] Toeplitz
    const float* __restrict__ bias,    // [OC*OH*OW]
    float* __restrict__ out)           // [B, OC*OH*OW]
{
    const int tid = threadIdx.x;
    const int blk = blockIdx.x;
    const int b   = blk >> 4;                 // batch
    const int sub = blk & 15;
    const int oc0 = (sub >> 1) << 1;          // 0,2,...,14
    const int hf  = sub & 1;                  // image half (rows 0-15 / 16-31)
    const int oh  = (hf << 4) + (tid >> 3);   // 0..31
    const int ow0 = (tid & 7) << 2;           // 0,4,...,28

    const float* xb = x + ((size_t)b << 13);  // this batch's image (8 KB floats)

    float a0[4] = {0.f, 0.f, 0.f, 0.f};
    float a1[4] = {0.f, 0.f, 0.f, 0.f};

    #pragma unroll
    for (int ic = 0; ic < IC; ++ic) {
        // ---- weights: block-uniform addresses -> scalar/broadcast loads ----
        float wv[2][9];
        #pragma unroll
        for (int os = 0; os < 2; ++os) {
            const int wbase = __builtin_amdgcn_readfirstlane(
                (oc0 + os) * (WCOLS << 10) + ic * 1156);   // (oc<<10)*WCOLS + ic*34*34
            #pragma unroll
            for (int kh = 0; kh < 3; ++kh)
                #pragma unroll
                for (int kw = 0; kw < 3; ++kw)
                    wv[os][kh * 3 + kw] = weight[(size_t)wbase + kh * 34 + kw];
        }

        // ---- 3 input rows, 6-col windows; branchless clamp + zero-select ----
        float w6[3][6];
        #pragma unroll
        for (int rr = 0; rr < 3; ++rr) {
            const int  row = oh + rr - 1;
            const bool ok  = (row >= 0) && (row < H);
            const int  rc  = (row < 0) ? 0 : ((row > 31) ? 31 : row);  // in-bounds addr
            const float* bp = xb + (ic << 10) + (rc << 5) + ow0;
            const float4 c  = *(const float4*)bp;                      // cols ow0..ow0+3
            const float  lf = *(bp + (ow0 > 0 ? -1 : 0));              // col ow0-1
            const float  rt = *(bp + (ow0 < 28 ? 4 : 0));              // col ow0+4
            w6[rr][0] = (ok && ow0 > 0)  ? lf  : 0.f;
            w6[rr][1] = ok ? c.x : 0.f;
            w6[rr][2] = ok ? c.y : 0.f;
            w6[rr][3] = ok ? c.z : 0.f;
            w6[rr][4] = ok ? c.w : 0.f;
            w6[rr][5] = (ok && ow0 < 28) ? rt  : 0.f;
        }

        // ---- 144 FMAs (fully unrolled, static indexing) ----
        #pragma unroll
        for (int kh = 0; kh < 3; ++kh) {
            const float v0 = w6[kh][0], v1 = w6[kh][1], v2 = w6[kh][2];
            const float v3 = w6[kh][3], v4 = w6[kh][4], v5 = w6[kh][5];
            {
                const float w0 = wv[0][kh * 3], w1 = wv[0][kh * 3 + 1], w2 = wv[0][kh * 3 + 2];
                a0[0] += v0 * w0 + v1 * w1 + v2 * w2;
                a0[1] += v1 * w0 + v2 * w1 + v3 * w2;
                a0[2] += v2 * w0 + v3 * w1 + v4 * w2;
                a0[3] += v3 * w0 + v4 * w1 + v5 * w2;
            }
            {
                const float w0 = wv[1][kh * 3], w1 = wv[1][kh * 3 + 1], w2 = wv[1][kh * 3 + 2];
                a1[0] += v0 * w0 + v1 * w1 + v2 * w2;
                a1[1] += v1 * w0 + v2 * w1 + v3 * w2;
                a1[2] += v2 * w0 + v3 * w1 + v4 * w2;
                a1[3] += v3 * w0 + v4 * w1 + v5 * w2;
            }
        }
    }

    // ---- epilogue: bias + b128 stores ----
    const int oidx = (oh << 5) + ow0;
    const float4 b0 = *(const float4*)(bias + (oc0 << 10) + oidx);
    const float4 b1 = *(const float4*)(bias + ((oc0 + 1) << 10) + oidx);
    float* op = out + (size_t)(((b << 4) + oc0) << 10) + oidx;
    *(float4*)op          = make_float4(a0[0] + b0.x, a0[1] + b0.y, a0[2] + b0.z, a0[3] + b0.w);
    *(float4*)(op + 1024) = make_float4(a1[0] + b1.x, a1[1] + b1.y, a1[2] + b1.z, a1[3] + b1.w);
}

extern "C" void kernel_launch(void* const* d_in, const int* in_sizes, int n_in,
                              void* d_out, int out_size, void* d_ws, size_t ws_size,
                              hipStream_t stream) {
    const float* x      = (const float*)d_in[0];  // enc_x  [64, 8192]
    const float* weight = (const float*)d_in[1];  // weight [16384, 9248]
    const float* bias   = (const float*)d_in[2];  // bias   [16384]
    // d_in[3] = pad_mat: realized via clamped addressing + zero-selects.
    float* out = (float*)d_out;                   // [64, 16384]

    conv_direct_kernel<<<dim3(BATCH * 16), dim3(128), 0, stream>>>(x, weight, bias, out);
}